// Round 11
// baseline (90.901 us; speedup 1.0000x reference)
//
#include <hip/hip_runtime.h>
#include <math.h>

#define EPSF 1e-6f

constexpr int B = 8, N = 2048, M = 16, S = 100;
constexpr int MAIN_BLOCKS = B * (N / 64);         // 256: pcl_to_prim, 64 points each
constexpr int PRIM_BLOCKS = B * M * 2;            // 256: prim_to_pcl, (b,m) x half-of-S
constexpr int TOTAL_BLOCKS = MAIN_BLOCKS + PRIM_BLOCKS;  // 512 worker blocks = 2/CU exact
constexpr int NPART = MAIN_BLOCKS * 4 + PRIM_BLOCKS;     // 1280 partials in d_ws

typedef float v2f __attribute__((ext_vector_type(2)));   // -> v_pk_fma_f32 pairs

// fast hw transcendentals (avoid __exp2f/__log2f: glibc math.h macro collision)
__device__ __forceinline__ float hw_exp2(float x) { return __builtin_amdgcn_exp2f(x); }
__device__ __forceinline__ float hw_log2(float x) { return __builtin_amdgcn_logf(x); }

__device__ __forceinline__ float sgn_d(float x) {
    return (x > 0.f) ? 1.f : ((x < 0.f) ? -1.f : 0.f);
}

// quaternion values (w,x,y,z) -> row-major 3x3 (value form so loads can be hoisted)
__device__ __forceinline__ void quat_Rv(float w, float x, float y, float z, float R[9]) {
    float inv = 1.0f / (sqrtf(w * w + x * x + y * y + z * z) + EPSF);
    w *= inv; x *= inv; y *= inv; z *= inv;
    R[0] = 1.f - 2.f * (y * y + z * z); R[1] = 2.f * (x * y - w * z); R[2] = 2.f * (x * z + w * y);
    R[3] = 2.f * (x * y + w * z); R[4] = 1.f - 2.f * (x * x + z * z); R[5] = 2.f * (y * z - w * x);
    R[6] = 2.f * (x * z - w * y); R[7] = 2.f * (y * z + w * x); R[8] = 1.f - 2.f * (x * x + y * y);
}

__device__ __forceinline__ void quat_R(const float* __restrict__ rot, int bm, float R[9]) {
    quat_Rv(rot[bm * 4 + 0], rot[bm * 4 + 1], rot[bm * 4 + 2], rot[bm * 4 + 3], R);
}

// ---------------- pre-kernel: stage all surface points ONCE ----------------
// R10 lesson: every main block recomputed its batch's 1600 points (32x
// redundancy chip-wide, worth ~2.5-3.5us by the R4 calibration). 8 blocks,
// one per batch; stream order makes k_all's reads safe (no flags needed).
// Same formulas as the R4-proven table path -> bit-identical staged values.
__global__ __launch_bounds__(256) void k_stage(
    const float* __restrict__ sizep, const float* __restrict__ seps,
    const float* __restrict__ deform, const float* __restrict__ etas,
    const float* __restrict__ omegas, float4* __restrict__ gpts)
{
    __shared__ __align__(16) float trig[S * 8];
    int t = threadIdx.x;
    int b = blockIdx.x;
    float4* trig4 = (float4*)trig;

    if (t < S) {
        float se_, ce_, sw_, cw_;
        __sincosf(etas[t], &se_, &ce_);
        __sincosf(omegas[t], &sw_, &cw_);
        float4 tA, tB;
        tA.x = hw_log2(fabsf(ce_) + EPSF); tA.y = sgn_d(ce_);
        tA.z = hw_log2(fabsf(se_) + EPSF); tA.w = sgn_d(se_);
        tB.x = hw_log2(fabsf(cw_) + EPSF); tB.y = sgn_d(cw_);
        tB.z = hw_log2(fabsf(sw_) + EPSF); tB.w = sgn_d(sw_);
        trig4[t * 2 + 0] = tA;
        trig4[t * 2 + 1] = tB;
    }
    __syncthreads();

    int m  = t & 15;
    int bmi = b * M + m;
    float e1 = seps[bmi * 2 + 0], e2 = seps[bmi * 2 + 1];
    float a1 = sizep[bmi * 3 + 0], a2 = sizep[bmi * 3 + 1], a3 = sizep[bmi * 3 + 2];
    float d0 = deform[bmi * 2 + 0], d1 = deform[bmi * 2 + 1];
    for (int s = t >> 4; s < S; s += 16) {
        float4 tA = trig4[s * 2 + 0];
        float4 tB = trig4[s * 2 + 1];
        float ce = tA.y * hw_exp2(e1 * tA.x);
        float se = tA.w * hw_exp2(e1 * tA.z);
        float cw = tB.y * hw_exp2(e2 * tB.x);
        float sw = tB.w * hw_exp2(e2 * tB.z);
        float x = a1 * ce * cw;
        float y = a2 * ce * sw;
        float z = a3 * se;
        float fx = fmaf(d0, se, 1.0f);   // z/a3 == se
        float fy = fmaf(d1, se, 1.0f);
        float4 P;
        P.x = fx * x; P.y = fy * y; P.z = z;
        P.w = P.x * P.x + P.y * P.y + P.z * P.z;
        gpts[b * (S * M) + s * M + m] = P;
    }
}

// ---------------- main fused kernel, 512 blocks = 2/CU ----------------
// [0,256): pcl_to_prim; [256,512): prim_to_pcl; reducer folded into block 511.
// Lessons: R6 don't grow the grid; R8 don't strip compute from latency-bound
// loops; R9/R10 cover latency. This round: staging phases replaced by one
// coalesced global->LDS copy (points precomputed by k_stage).
__global__ __launch_bounds__(256) void k_all(
    const float* __restrict__ pcl, const float* __restrict__ trans,
    const float* __restrict__ rot, const float* __restrict__ sizep,
    const float* __restrict__ probs, const float4* __restrict__ gpts,
    float* __restrict__ part, unsigned int* __restrict__ flags,
    float* __restrict__ out)
{
    __shared__ float4 pts[S * M];   // 25.6 KB  (prim path reuses [0..49])
    __shared__ float sbuf[20];      // prim: sarea[0..15], wsum[16..19]

    int t = threadIdx.x;

    if (blockIdx.x < MAIN_BLOCKS) {
        // ---------- pcl_to_prim ----------
        int b  = blockIdx.x >> 5;        // 32 n-chunks per batch
        int n0 = (blockIdx.x & 31) * 64;
        int m  = t & 15;
        int nl = t >> 4;
        int bm = b * M + m;

        // EARLY register loads: in flight under the LDS-copy phase.
        float qw = rot[bm * 4 + 0], qx = rot[bm * 4 + 1];
        float qy = rot[bm * 4 + 2], qz = rot[bm * 4 + 3];
        float tx = trans[bm * 3 + 0], ty = trans[bm * 3 + 1], tz = trans[bm * 3 + 2];
        float plx[4], ply[4], plz[4];
#pragma unroll
        for (int j = 0; j < 4; j++) {
            int n = n0 + nl + 16 * j;
            plx[j] = pcl[(b * N + n) * 3 + 0];
            ply[j] = pcl[(b * N + n) * 3 + 1];
            plz[j] = pcl[(b * N + n) * 3 + 2];
        }
        float pv = probs[bm];

        // staged points: one coalesced copy (1KB/wave-instr), ONE barrier
        // (replaces stage1+stage2+2 barriers of R10).
        {
            const float4* src = gpts + b * (S * M);
            for (int i = t; i < S * M; i += 256) pts[i] = src[i];
        }
        __syncthreads();

        float R[9];
        quat_Rv(qw, qx, qy, qz, R);

        // rotated points; j packed in pairs for v_pk_fma_f32
        v2f mx2[2], my2[2], mz2[2], dmin2[2];
        float psq[4];
#pragma unroll
        for (int j = 0; j < 4; j++) {
            float dx = plx[j] - tx, dy = ply[j] - ty, dz = plz[j] - tz;
            float X = R[0] * dx + R[1] * dy + R[2] * dz;
            float Y = R[3] * dx + R[4] * dy + R[5] * dz;
            float Z = R[6] * dx + R[7] * dy + R[8] * dz;
            mx2[j >> 1][j & 1] = -2.f * X;
            my2[j >> 1][j & 1] = -2.f * Y;
            mz2[j >> 1][j & 1] = -2.f * Z;
            psq[j] = X * X + Y * Y + Z * Z;
            dmin2[j >> 1][j & 1] = 3.4e38f;
        }

        // min over s of (|P|^2 - 2 P.pt); 8-wide two-bank ping-pong (R10);
        // s ascending everywhere -> bit-identical accumulation order.
        auto compute4 = [&](const float4* P4) {
#pragma unroll
            for (int u = 0; u < 4; u++) {
                float4 P = P4[u];
                v2f vx = {P.x, P.x}, vy = {P.y, P.y}, vz = {P.z, P.z}, vw = {P.w, P.w};
#pragma unroll
                for (int p = 0; p < 2; p++) {
                    v2f d = __builtin_elementwise_fma(vx, mx2[p], vw);
                    d = __builtin_elementwise_fma(vy, my2[p], d);
                    d = __builtin_elementwise_fma(vz, mz2[p], d);
                    dmin2[p] = __builtin_elementwise_min(dmin2[p], d);
                }
            }
        };
        auto load8 = [&](float4* dst, int sbase) {
#pragma unroll
            for (int u = 0; u < 8; u++) dst[u] = pts[(sbase + u) * M + m];
        };

        float4 Abank[8], Bbank[8];
        load8(Abank, 0);
        for (int gp = 0; gp < 6; gp++) {            // 12 groups of 8 = s 0..95
            load8(Bbank, (2 * gp + 1) * 8);
            compute4(Abank); compute4(Abank + 4);
            if (gp < 5) load8(Abank, (2 * gp + 2) * 8);
            else {
#pragma unroll
                for (int u = 0; u < 4; u++) Abank[u] = pts[(96 + u) * M + m];
            }
            compute4(Bbank); compute4(Bbank + 4);
        }
        compute4(Abank);                            // s = 96..99

        // ---- in-wave cumprod-sorted sum (order identical to prior rounds) ----
        float ompr[16];
#pragma unroll
        for (int k = 0; k < 16; k++) ompr[k] = 1.f - probs[b * M + k];
        float acc = 0.f;
#pragma unroll
        for (int j = 0; j < 4; j++) {
            float key = dmin2[j >> 1][j & 1] + psq[j];
            float prod = 1.f;
#pragma unroll
            for (int k = 0; k < 16; k++) {
                float bk = __shfl(key, k, 16);
                bool before = (bk < key) || (bk == key && k < m);
                prod *= before ? ompr[k] : 1.f;
            }
            acc += key * pv * prod;
        }
        for (int off = 32; off >= 1; off >>= 1) acc += __shfl_down(acc, off);
        if ((t & 63) == 0)
            __hip_atomic_store(&part[blockIdx.x * 4 + (t >> 6)],
                               acc * (1.0f / (B * N)),
                               __ATOMIC_RELAXED, __HIP_MEMORY_SCOPE_AGENT);
        __syncthreads();   // all four partial stores issued before flag
        if (t == 0)
            __hip_atomic_store(&flags[blockIdx.x], 1u,
                               __ATOMIC_RELEASE, __HIP_MEMORY_SCOPE_AGENT);
    } else {
        // ---------- prim_to_pcl ----------
        int pb = blockIdx.x - MAIN_BLOCKS;
        int bm = pb >> 1, q = pb & 1;
        int b = bm >> 4, m = bm & 15;
        int s0 = q * 50;

        float4* spts = pts;          // [0..49]
        float* sarea = sbuf;         // [0..15]
        float* wsum  = sbuf + 16;    // [16..19]

        // staged points from k_stage (replaces 12-transcendental surf_point x50)
        if (t < 50) spts[t] = gpts[b * (S * M) + (s0 + t) * M + m];
        if (t >= 64 && t < 64 + M) {
            int mm = t - 64;
            float s0s = sizep[(b * M + mm) * 3 + 0];
            float s1s = sizep[(b * M + mm) * 3 + 1];
            float s2s = sizep[(b * M + mm) * 3 + 2];
            float tt = __powf(s0s * s1s, 1.6f) / 3.f + __powf(s0s * s2s, 1.6f) / 3.f
                     + __powf(s1s * s2s, 1.6f) / 3.f;
            sarea[mm] = 4.0f * 3.14159265358979323846f * __powf(tt, 0.625f);
        }
        __syncthreads();

        float R[9];
        quat_R(rot, bm, R);
        float tx = trans[bm * 3 + 0], ty = trans[bm * 3 + 1], tz = trans[bm * 3 + 2];

        int w = t >> 6, lane = t & 63;
        int cnt = (w < 2) ? 13 : 12;
        int off = (w < 2) ? w * 13 : 26 + (w - 2) * 12;

        // 14 slots packed into 7 v2f pairs (pads map to slot 'off', masked later)
        v2f px2[7], py2[7], pz2[7], mins2[7];
#pragma unroll
        for (int k = 0; k < 14; k++) {
            int sl = (k < cnt) ? (off + k) : off;
            float4 P = spts[sl];
            px2[k >> 1][k & 1] = P.x;
            py2[k >> 1][k & 1] = P.y;
            pz2[k >> 1][k & 1] = P.z;
            mins2[k >> 1][k & 1] = 3.4e38f;
        }

        // min over n, 32 iters in 8 groups of 4; 4-iteration-deep register
        // prefetch (two named banks, static indexing only): round-9 win.
        const float* pcb = pcl + b * N * 3 + lane * 3;

#define LOADG(x0,y0,z0,x1,y1,z1,x2,y2,z2,x3,y3,z3, g)            \
        { const float* p_ = pcb + (g) * 768;                     \
          x0 = p_[0];   y0 = p_[1];   z0 = p_[2];                \
          x1 = p_[192]; y1 = p_[193]; z1 = p_[194];              \
          x2 = p_[384]; y2 = p_[385]; z2 = p_[386];              \
          x3 = p_[576]; y3 = p_[577]; z3 = p_[578]; }

#define COMP1(cx,cy,cz)                                          \
        { float dx = (cx) - tx, dy = (cy) - ty, dz = (cz) - tz;  \
          float X = R[0] * dx + R[1] * dy + R[2] * dz;           \
          float Y = R[3] * dx + R[4] * dy + R[5] * dz;           \
          float Z = R[6] * dx + R[7] * dy + R[8] * dz;           \
          float Xsq = X * X + Y * Y + Z * Z;                     \
          v2f vmX = {-2.f * X, -2.f * X}, vmY = {-2.f * Y, -2.f * Y}; \
          v2f vmZ = {-2.f * Z, -2.f * Z}, vXq = {Xsq, Xsq};      \
          _Pragma("unroll")                                      \
          for (int k = 0; k < 7; k++) {                          \
              v2f d = __builtin_elementwise_fma(px2[k], vmX, vXq); \
              d = __builtin_elementwise_fma(py2[k], vmY, d);     \
              d = __builtin_elementwise_fma(pz2[k], vmZ, d);     \
              mins2[k] = __builtin_elementwise_min(mins2[k], d); \
          } }

#define COMPG(x0,y0,z0,x1,y1,z1,x2,y2,z2,x3,y3,z3)               \
        COMP1(x0,y0,z0) COMP1(x1,y1,z1) COMP1(x2,y2,z2) COMP1(x3,y3,z3)

        float a0x,a0y,a0z,a1x,a1y,a1z,a2x,a2y,a2z,a3x,a3y,a3z;
        float b0x,b0y,b0z,b1x,b1y,b1z,b2x,b2y,b2z,b3x,b3y,b3z;

        LOADG(a0x,a0y,a0z,a1x,a1y,a1z,a2x,a2y,a2z,a3x,a3y,a3z, 0)
        LOADG(b0x,b0y,b0z,b1x,b1y,b1z,b2x,b2y,b2z,b3x,b3y,b3z, 1)
        COMPG(a0x,a0y,a0z,a1x,a1y,a1z,a2x,a2y,a2z,a3x,a3y,a3z)
        LOADG(a0x,a0y,a0z,a1x,a1y,a1z,a2x,a2y,a2z,a3x,a3y,a3z, 2)
        COMPG(b0x,b0y,b0z,b1x,b1y,b1z,b2x,b2y,b2z,b3x,b3y,b3z)
        LOADG(b0x,b0y,b0z,b1x,b1y,b1z,b2x,b2y,b2z,b3x,b3y,b3z, 3)
        COMPG(a0x,a0y,a0z,a1x,a1y,a1z,a2x,a2y,a2z,a3x,a3y,a3z)
        LOADG(a0x,a0y,a0z,a1x,a1y,a1z,a2x,a2y,a2z,a3x,a3y,a3z, 4)
        COMPG(b0x,b0y,b0z,b1x,b1y,b1z,b2x,b2y,b2z,b3x,b3y,b3z)
        LOADG(b0x,b0y,b0z,b1x,b1y,b1z,b2x,b2y,b2z,b3x,b3y,b3z, 5)
        COMPG(a0x,a0y,a0z,a1x,a1y,a1z,a2x,a2y,a2z,a3x,a3y,a3z)
        LOADG(a0x,a0y,a0z,a1x,a1y,a1z,a2x,a2y,a2z,a3x,a3y,a3z, 6)
        COMPG(b0x,b0y,b0z,b1x,b1y,b1z,b2x,b2y,b2z,b3x,b3y,b3z)
        LOADG(b0x,b0y,b0z,b1x,b1y,b1z,b2x,b2y,b2z,b3x,b3y,b3z, 7)
        COMPG(a0x,a0y,a0z,a1x,a1y,a1z,a2x,a2y,a2z,a3x,a3y,a3z)
        COMPG(b0x,b0y,b0z,b1x,b1y,b1z,b2x,b2y,b2z,b3x,b3y,b3z)

#undef LOADG
#undef COMP1
#undef COMPG

        float sum = 0.f;
#pragma unroll
        for (int k = 0; k < 14; k++) {
            float v = mins2[k >> 1][k & 1];
            for (int o = 32; o >= 1; o >>= 1) v = fminf(v, __shfl_down(v, o));
            int sl = (k < cnt) ? (off + k) : off;
            v += spts[sl].w;                       // add back |P_k|^2
            sum += (k < cnt) ? v : 0.f;
        }

        if (lane == 0) wsum[w] = sum;
        __syncthreads();
        if (t == 0) {
            float total = wsum[0] + wsum[1] + wsum[2] + wsum[3];
            float asum = 0.f;
            for (int mm = 0; mm < M; mm++) asum += sarea[mm];
            float area = (float)M * sarea[m] / asum;
            __hip_atomic_store(&part[MAIN_BLOCKS * 4 + pb],
                               total * area * (1.0f / (S * B * M)),
                               __ATOMIC_RELAXED, __HIP_MEMORY_SCOPE_AGENT);
            __hip_atomic_store(&flags[blockIdx.x], 1u,
                               __ATOMIC_RELEASE, __HIP_MEMORY_SCOPE_AGENT);
        }

        // ---------- reducer folded into the LAST prim block ----------
        if (blockIdx.x == TOTAL_BLOCKS - 1 && t < 64) {
            for (int i = t; i < TOTAL_BLOCKS; i += 64) {
                while (__hip_atomic_load(&flags[i], __ATOMIC_ACQUIRE,
                                         __HIP_MEMORY_SCOPE_AGENT) != 1u)
                    __builtin_amdgcn_s_sleep(2);
            }
            __threadfence();
            float ssum = 0.f;
            for (int i = t; i < NPART; i += 64)
                ssum += __hip_atomic_load(&part[i], __ATOMIC_RELAXED,
                                          __HIP_MEMORY_SCOPE_AGENT);
            for (int off = 32; off >= 1; off >>= 1) ssum += __shfl_down(ssum, off);
            if (t == 0) out[0] = ssum;
            // self-reset so replay is correct even if ws poisoning is skipped
            for (int i = t; i < TOTAL_BLOCKS; i += 64)
                __hip_atomic_store(&flags[i], 0u, __ATOMIC_RELAXED,
                                   __HIP_MEMORY_SCOPE_AGENT);
        }
    }
}

extern "C" void kernel_launch(void* const* d_in, const int* in_sizes, int n_in,
                              void* d_out, int out_size, void* d_ws, size_t ws_size,
                              hipStream_t stream)
{
    const float* pcl    = (const float*)d_in[0];
    const float* trans  = (const float*)d_in[1];
    const float* rot    = (const float*)d_in[2];
    const float* sizep  = (const float*)d_in[3];
    const float* seps   = (const float*)d_in[4];
    const float* deform = (const float*)d_in[5];
    const float* probs  = (const float*)d_in[6];
    const float* etas   = (const float*)d_in[7];
    const float* omegas = (const float*)d_in[8];
    float* out = (float*)d_out;
    float* partials = (float*)d_ws;                       // [0, 5120) bytes
    unsigned int* flags = (unsigned int*)((char*)d_ws + 8192);   // [8192, 10240)
    float4* gpts = (float4*)((char*)d_ws + 16384);        // [16K, 16K+204.8K)

    k_stage<<<B, 256, 0, stream>>>(sizep, seps, deform, etas, omegas, gpts);
    k_all<<<TOTAL_BLOCKS, 256, 0, stream>>>(pcl, trans, rot, sizep, probs, gpts,
                                            partials, flags, out);
}

// Round 12
// 87.562 us; speedup vs baseline: 1.0381x; 1.0381x over previous
//
#include <hip/hip_runtime.h>
#include <math.h>

#define EPSF 1e-6f

constexpr int B = 8, N = 2048, M = 16, S = 100;
constexpr int MAIN_BLOCKS = B * (N / 64);         // 256: pcl_to_prim, 64 points each
constexpr int PRIM_BLOCKS = B * M * 2;            // 256: prim_to_pcl, (b,m) x half-of-S
constexpr int TOTAL_BLOCKS = MAIN_BLOCKS + PRIM_BLOCKS;  // 512 worker blocks = 2/CU exact
constexpr int NPART = MAIN_BLOCKS * 4 + PRIM_BLOCKS;     // 1280 partials in d_ws

typedef float v2f __attribute__((ext_vector_type(2)));   // -> v_pk_fma_f32 pairs

// fast hw transcendentals (avoid __exp2f/__log2f: glibc math.h macro collision)
__device__ __forceinline__ float hw_exp2(float x) { return __builtin_amdgcn_exp2f(x); }
__device__ __forceinline__ float hw_log2(float x) { return __builtin_amdgcn_logf(x); }

__device__ __forceinline__ float fexp_d(float x, float p) {
    float sg = (x > 0.f) ? 1.f : ((x < 0.f) ? -1.f : 0.f);
    return sg * __powf(fabsf(x) + EPSF, p);
}

__device__ __forceinline__ float sgn_d(float x) {
    return (x > 0.f) ? 1.f : ((x < 0.f) ? -1.f : 0.f);
}

// quaternion values (w,x,y,z) -> row-major 3x3 (value form so loads can be hoisted)
__device__ __forceinline__ void quat_Rv(float w, float x, float y, float z, float R[9]) {
    float inv = 1.0f / (sqrtf(w * w + x * x + y * y + z * z) + EPSF);
    w *= inv; x *= inv; y *= inv; z *= inv;
    R[0] = 1.f - 2.f * (y * y + z * z); R[1] = 2.f * (x * y - w * z); R[2] = 2.f * (x * z + w * y);
    R[3] = 2.f * (x * y + w * z); R[4] = 1.f - 2.f * (x * x + z * z); R[5] = 2.f * (y * z - w * x);
    R[6] = 2.f * (x * z - w * y); R[7] = 2.f * (y * z + w * x); R[8] = 1.f - 2.f * (x * x + y * y);
}

__device__ __forceinline__ void quat_R(const float* __restrict__ rot, int bm, float R[9]) {
    quat_Rv(rot[bm * 4 + 0], rot[bm * 4 + 1], rot[bm * 4 + 2], rot[bm * 4 + 3], R);
}

// surface point (prim path; 50 pts/block, transcendental cost irrelevant there)
__device__ __forceinline__ float4 surf_point(
    const float* __restrict__ sizep, const float* __restrict__ seps,
    const float* __restrict__ deform, const float* __restrict__ etas,
    const float* __restrict__ omegas, int bm, int s)
{
    float e1 = seps[bm * 2 + 0], e2 = seps[bm * 2 + 1];
    float a1 = sizep[bm * 3 + 0], a2 = sizep[bm * 3 + 1], a3 = sizep[bm * 3 + 2];
    float d0 = deform[bm * 2 + 0], d1 = deform[bm * 2 + 1];
    float se_, ce_, sw_, cw_;
    __sincosf(etas[s], &se_, &ce_);
    __sincosf(omegas[s], &sw_, &cw_);
    float ce = fexp_d(ce_, e1);
    float se = fexp_d(se_, e1);
    float cw = fexp_d(cw_, e2);
    float sw = fexp_d(sw_, e2);
    float x = a1 * ce * cw;
    float y = a2 * ce * sw;
    float z = a3 * se;
    float fx = d0 * (z / a3) + 1.0f;
    float fy = d1 * (z / a3) + 1.0f;
    float4 P;
    P.x = fx * x; P.y = fy * y; P.z = z;
    P.w = P.x * P.x + P.y * P.y + P.z * P.z;
    return P;
}

// ---------------- single fused kernel, 512 blocks = 2/CU ----------------
// Measured-best configuration (round 10, 88.93us). Structure is final:
// [0,256): pcl_to_prim; [256,512): prim_to_pcl; reducer folded into block 511.
// Session lessons encoded:
//  R1: no same-address atomic bursts (~14ns each, serialized).
//  R6/R11: no extra grid blocks, no extra serial dispatch nodes (~2us each).
//  R8: don't strip compute from latency-bound loops (exposes stall).
//  R9/R10: DO cover latency: register prefetch (global), deep LDS ping-pong,
//          early hoisted loads; keep accumulation order bit-identical.
__global__ __launch_bounds__(256) void k_all(
    const float* __restrict__ pcl, const float* __restrict__ trans,
    const float* __restrict__ rot, const float* __restrict__ sizep,
    const float* __restrict__ seps, const float* __restrict__ deform,
    const float* __restrict__ probs,
    const float* __restrict__ etas, const float* __restrict__ omegas,
    float* __restrict__ part, unsigned int* __restrict__ flags,
    float* __restrict__ out)
{
    __shared__ float4 pts[S * M];            // 25.6 KB  (prim path reuses [0..49])
    __shared__ __align__(16) float trig[S * 8];  // 3.2 KB per-s {log2|c|,sgn}x4
    __shared__ float sbuf[20];               // prim: sarea[0..15], wsum[16..19]

    int t = threadIdx.x;

    if (blockIdx.x < MAIN_BLOCKS) {
        // ---------- pcl_to_prim ----------
        int b  = blockIdx.x >> 5;        // 32 n-chunks per batch
        int n0 = (blockIdx.x & 31) * 64;
        int m  = t & 15;
        int nl = t >> 4;
        int bm = b * M + m;

        // EARLY register loads: in flight under stage-1/2 staging (covers the
        // ~600cyc global-load bubble that used to sit after the 2nd barrier).
        float qw = rot[bm * 4 + 0], qx = rot[bm * 4 + 1];
        float qy = rot[bm * 4 + 2], qz = rot[bm * 4 + 3];
        float tx = trans[bm * 3 + 0], ty = trans[bm * 3 + 1], tz = trans[bm * 3 + 2];
        float plx[4], ply[4], plz[4];
#pragma unroll
        for (int j = 0; j < 4; j++) {
            int n = n0 + nl + 16 * j;
            plx[j] = pcl[(b * N + n) * 3 + 0];
            ply[j] = pcl[(b * N + n) * 3 + 1];
            plz[j] = pcl[(b * N + n) * 3 + 2];
        }
        float pv = probs[bm];

        // stage 1: per-s trig+log table (sincos/log depend only on s, not m)
        float4* trig4 = (float4*)trig;
        if (t < S) {
            float se_, ce_, sw_, cw_;
            __sincosf(etas[t], &se_, &ce_);
            __sincosf(omegas[t], &sw_, &cw_);
            float4 tA, tB;
            tA.x = hw_log2(fabsf(ce_) + EPSF); tA.y = sgn_d(ce_);
            tA.z = hw_log2(fabsf(se_) + EPSF); tA.w = sgn_d(se_);
            tB.x = hw_log2(fabsf(cw_) + EPSF); tB.y = sgn_d(cw_);
            tB.z = hw_log2(fabsf(sw_) + EPSF); tB.w = sgn_d(sw_);
            trig4[t * 2 + 0] = tA;
            trig4[t * 2 + 1] = tB;
        }
        __syncthreads();

        // stage 2: 1600 surface points, 4 exp2 each. m-index (i&15) is
        // loop-invariant -> per-m params hoisted; trig read as 2x float4.
        {
            float e1 = seps[bm * 2 + 0], e2 = seps[bm * 2 + 1];
            float a1 = sizep[bm * 3 + 0], a2 = sizep[bm * 3 + 1], a3 = sizep[bm * 3 + 2];
            float d0 = deform[bm * 2 + 0], d1 = deform[bm * 2 + 1];
            for (int s = nl; s < S; s += 16) {
                float4 tA = trig4[s * 2 + 0];
                float4 tB = trig4[s * 2 + 1];
                float ce = tA.y * hw_exp2(e1 * tA.x);
                float se = tA.w * hw_exp2(e1 * tA.z);
                float cw = tB.y * hw_exp2(e2 * tB.x);
                float sw = tB.w * hw_exp2(e2 * tB.z);
                float x = a1 * ce * cw;
                float y = a2 * ce * sw;
                float z = a3 * se;
                float fx = fmaf(d0, se, 1.0f);   // z/a3 == se
                float fy = fmaf(d1, se, 1.0f);
                float4 P;
                P.x = fx * x; P.y = fy * y; P.z = z;
                P.w = P.x * P.x + P.y * P.y + P.z * P.z;
                pts[s * M + m] = P;
            }
        }
        __syncthreads();

        float R[9];
        quat_Rv(qw, qx, qy, qz, R);

        // rotated points; j packed in pairs for v_pk_fma_f32
        v2f mx2[2], my2[2], mz2[2], dmin2[2];
        float psq[4];
#pragma unroll
        for (int j = 0; j < 4; j++) {
            float dx = plx[j] - tx, dy = ply[j] - ty, dz = plz[j] - tz;
            float X = R[0] * dx + R[1] * dy + R[2] * dz;
            float Y = R[3] * dx + R[4] * dy + R[5] * dz;
            float Z = R[6] * dx + R[7] * dy + R[8] * dz;
            mx2[j >> 1][j & 1] = -2.f * X;
            my2[j >> 1][j & 1] = -2.f * Y;
            mz2[j >> 1][j & 1] = -2.f * Z;
            psq[j] = X * X + Y * Y + Z * Z;
            dmin2[j >> 1][j & 1] = 3.4e38f;
        }

        // min over s of (|P|^2 - 2 P.pt); 8-wide two-bank ping-pong:
        // 8 ds_read_b128 in flight under 128cyc of compute fully covers the
        // ~120cyc LDS latency. s ascending -> bit-identical accumulation order.
        auto compute4 = [&](const float4* P4) {
#pragma unroll
            for (int u = 0; u < 4; u++) {
                float4 P = P4[u];
                v2f vx = {P.x, P.x}, vy = {P.y, P.y}, vz = {P.z, P.z}, vw = {P.w, P.w};
#pragma unroll
                for (int p = 0; p < 2; p++) {
                    v2f d = __builtin_elementwise_fma(vx, mx2[p], vw);
                    d = __builtin_elementwise_fma(vy, my2[p], d);
                    d = __builtin_elementwise_fma(vz, mz2[p], d);
                    dmin2[p] = __builtin_elementwise_min(dmin2[p], d);
                }
            }
        };
        auto load8 = [&](float4* dst, int sbase) {
#pragma unroll
            for (int u = 0; u < 8; u++) dst[u] = pts[(sbase + u) * M + m];
        };

        float4 Abank[8], Bbank[8];
        load8(Abank, 0);
        for (int gp = 0; gp < 6; gp++) {            // 12 groups of 8 = s 0..95
            load8(Bbank, (2 * gp + 1) * 8);
            compute4(Abank); compute4(Abank + 4);
            if (gp < 5) load8(Abank, (2 * gp + 2) * 8);
            else {
#pragma unroll
                for (int u = 0; u < 4; u++) Abank[u] = pts[(96 + u) * M + m];
            }
            compute4(Bbank); compute4(Bbank + 4);
        }
        compute4(Abank);                            // s = 96..99

        // ---- in-wave cumprod-sorted sum (order identical to prior rounds) ----
        float ompr[16];
#pragma unroll
        for (int k = 0; k < 16; k++) ompr[k] = 1.f - probs[b * M + k];
        float acc = 0.f;
#pragma unroll
        for (int j = 0; j < 4; j++) {
            float key = dmin2[j >> 1][j & 1] + psq[j];
            float prod = 1.f;
#pragma unroll
            for (int k = 0; k < 16; k++) {
                float bk = __shfl(key, k, 16);
                bool before = (bk < key) || (bk == key && k < m);
                prod *= before ? ompr[k] : 1.f;
            }
            acc += key * pv * prod;
        }
        for (int off = 32; off >= 1; off >>= 1) acc += __shfl_down(acc, off);
        if ((t & 63) == 0)
            __hip_atomic_store(&part[blockIdx.x * 4 + (t >> 6)],
                               acc * (1.0f / (B * N)),
                               __ATOMIC_RELAXED, __HIP_MEMORY_SCOPE_AGENT);
        __syncthreads();   // all four partial stores issued before flag
        if (t == 0)
            __hip_atomic_store(&flags[blockIdx.x], 1u,
                               __ATOMIC_RELEASE, __HIP_MEMORY_SCOPE_AGENT);
    } else {
        // ---------- prim_to_pcl ----------
        int pb = blockIdx.x - MAIN_BLOCKS;
        int bm = pb >> 1, q = pb & 1;
        int b = bm >> 4, m = bm & 15;
        int s0 = q * 50;

        float4* spts = pts;          // [0..49]
        float* sarea = sbuf;         // [0..15]
        float* wsum  = sbuf + 16;    // [16..19]

        if (t < 50) spts[t] = surf_point(sizep, seps, deform, etas, omegas, bm, s0 + t);
        if (t >= 64 && t < 64 + M) {
            int mm = t - 64;
            float s0s = sizep[(b * M + mm) * 3 + 0];
            float s1s = sizep[(b * M + mm) * 3 + 1];
            float s2s = sizep[(b * M + mm) * 3 + 2];
            float tt = __powf(s0s * s1s, 1.6f) / 3.f + __powf(s0s * s2s, 1.6f) / 3.f
                     + __powf(s1s * s2s, 1.6f) / 3.f;
            sarea[mm] = 4.0f * 3.14159265358979323846f * __powf(tt, 0.625f);
        }
        __syncthreads();

        float R[9];
        quat_R(rot, bm, R);
        float tx = trans[bm * 3 + 0], ty = trans[bm * 3 + 1], tz = trans[bm * 3 + 2];

        int w = t >> 6, lane = t & 63;
        int cnt = (w < 2) ? 13 : 12;
        int off = (w < 2) ? w * 13 : 26 + (w - 2) * 12;

        // 14 slots packed into 7 v2f pairs (pads map to slot 'off', masked later)
        v2f px2[7], py2[7], pz2[7], mins2[7];
#pragma unroll
        for (int k = 0; k < 14; k++) {
            int sl = (k < cnt) ? (off + k) : off;
            float4 P = spts[sl];
            px2[k >> 1][k & 1] = P.x;
            py2[k >> 1][k & 1] = P.y;
            pz2[k >> 1][k & 1] = P.z;
            mins2[k >> 1][k & 1] = 3.4e38f;
        }

        // min over n, 32 iters in 8 groups of 4; 4-iteration-deep register
        // prefetch (two named banks, static indexing only): 12 loads of group
        // g+1 in flight across ~490cyc of group-g compute (round-9 win).
        const float* pcb = pcl + b * N * 3 + lane * 3;

#define LOADG(x0,y0,z0,x1,y1,z1,x2,y2,z2,x3,y3,z3, g)            \
        { const float* p_ = pcb + (g) * 768;                     \
          x0 = p_[0];   y0 = p_[1];   z0 = p_[2];                \
          x1 = p_[192]; y1 = p_[193]; z1 = p_[194];              \
          x2 = p_[384]; y2 = p_[385]; z2 = p_[386];              \
          x3 = p_[576]; y3 = p_[577]; z3 = p_[578]; }

#define COMP1(cx,cy,cz)                                          \
        { float dx = (cx) - tx, dy = (cy) - ty, dz = (cz) - tz;  \
          float X = R[0] * dx + R[1] * dy + R[2] * dz;           \
          float Y = R[3] * dx + R[4] * dy + R[5] * dz;           \
          float Z = R[6] * dx + R[7] * dy + R[8] * dz;           \
          float Xsq = X * X + Y * Y + Z * Z;                     \
          v2f vmX = {-2.f * X, -2.f * X}, vmY = {-2.f * Y, -2.f * Y}; \
          v2f vmZ = {-2.f * Z, -2.f * Z}, vXq = {Xsq, Xsq};      \
          _Pragma("unroll")                                      \
          for (int k = 0; k < 7; k++) {                          \
              v2f d = __builtin_elementwise_fma(px2[k], vmX, vXq); \
              d = __builtin_elementwise_fma(py2[k], vmY, d);     \
              d = __builtin_elementwise_fma(pz2[k], vmZ, d);     \
              mins2[k] = __builtin_elementwise_min(mins2[k], d); \
          } }

#define COMPG(x0,y0,z0,x1,y1,z1,x2,y2,z2,x3,y3,z3)               \
        COMP1(x0,y0,z0) COMP1(x1,y1,z1) COMP1(x2,y2,z2) COMP1(x3,y3,z3)

        float a0x,a0y,a0z,a1x,a1y,a1z,a2x,a2y,a2z,a3x,a3y,a3z;
        float b0x,b0y,b0z,b1x,b1y,b1z,b2x,b2y,b2z,b3x,b3y,b3z;

        LOADG(a0x,a0y,a0z,a1x,a1y,a1z,a2x,a2y,a2z,a3x,a3y,a3z, 0)
        LOADG(b0x,b0y,b0z,b1x,b1y,b1z,b2x,b2y,b2z,b3x,b3y,b3z, 1)
        COMPG(a0x,a0y,a0z,a1x,a1y,a1z,a2x,a2y,a2z,a3x,a3y,a3z)
        LOADG(a0x,a0y,a0z,a1x,a1y,a1z,a2x,a2y,a2z,a3x,a3y,a3z, 2)
        COMPG(b0x,b0y,b0z,b1x,b1y,b1z,b2x,b2y,b2z,b3x,b3y,b3z)
        LOADG(b0x,b0y,b0z,b1x,b1y,b1z,b2x,b2y,b2z,b3x,b3y,b3z, 3)
        COMPG(a0x,a0y,a0z,a1x,a1y,a1z,a2x,a2y,a2z,a3x,a3y,a3z)
        LOADG(a0x,a0y,a0z,a1x,a1y,a1z,a2x,a2y,a2z,a3x,a3y,a3z, 4)
        COMPG(b0x,b0y,b0z,b1x,b1y,b1z,b2x,b2y,b2z,b3x,b3y,b3z)
        LOADG(b0x,b0y,b0z,b1x,b1y,b1z,b2x,b2y,b2z,b3x,b3y,b3z, 5)
        COMPG(a0x,a0y,a0z,a1x,a1y,a1z,a2x,a2y,a2z,a3x,a3y,a3z)
        LOADG(a0x,a0y,a0z,a1x,a1y,a1z,a2x,a2y,a2z,a3x,a3y,a3z, 6)
        COMPG(b0x,b0y,b0z,b1x,b1y,b1z,b2x,b2y,b2z,b3x,b3y,b3z)
        LOADG(b0x,b0y,b0z,b1x,b1y,b1z,b2x,b2y,b2z,b3x,b3y,b3z, 7)
        COMPG(a0x,a0y,a0z,a1x,a1y,a1z,a2x,a2y,a2z,a3x,a3y,a3z)
        COMPG(b0x,b0y,b0z,b1x,b1y,b1z,b2x,b2y,b2z,b3x,b3y,b3z)

#undef LOADG
#undef COMP1
#undef COMPG

        float sum = 0.f;
#pragma unroll
        for (int k = 0; k < 14; k++) {
            float v = mins2[k >> 1][k & 1];
            for (int o = 32; o >= 1; o >>= 1) v = fminf(v, __shfl_down(v, o));
            int sl = (k < cnt) ? (off + k) : off;
            v += spts[sl].w;                       // add back |P_k|^2
            sum += (k < cnt) ? v : 0.f;
        }

        if (lane == 0) wsum[w] = sum;
        __syncthreads();
        if (t == 0) {
            float total = wsum[0] + wsum[1] + wsum[2] + wsum[3];
            float asum = 0.f;
            for (int mm = 0; mm < M; mm++) asum += sarea[mm];
            float area = (float)M * sarea[m] / asum;
            __hip_atomic_store(&part[MAIN_BLOCKS * 4 + pb],
                               total * area * (1.0f / (S * B * M)),
                               __ATOMIC_RELAXED, __HIP_MEMORY_SCOPE_AGENT);
            __hip_atomic_store(&flags[blockIdx.x], 1u,
                               __ATOMIC_RELEASE, __HIP_MEMORY_SCOPE_AGENT);
        }

        // ---------- reducer folded into the LAST prim block ----------
        // All 512 worker blocks are co-resident (2/CU, LDS 29KB -> cap 5/CU),
        // and the reducer only waits on workers (never the reverse) -> safe.
        if (blockIdx.x == TOTAL_BLOCKS - 1 && t < 64) {
            for (int i = t; i < TOTAL_BLOCKS; i += 64) {
                while (__hip_atomic_load(&flags[i], __ATOMIC_ACQUIRE,
                                         __HIP_MEMORY_SCOPE_AGENT) != 1u)
                    __builtin_amdgcn_s_sleep(2);
            }
            __threadfence();
            float ssum = 0.f;
            for (int i = t; i < NPART; i += 64)
                ssum += __hip_atomic_load(&part[i], __ATOMIC_RELAXED,
                                          __HIP_MEMORY_SCOPE_AGENT);
            for (int off = 32; off >= 1; off >>= 1) ssum += __shfl_down(ssum, off);
            if (t == 0) out[0] = ssum;
            // self-reset so replay is correct even if ws poisoning is skipped
            for (int i = t; i < TOTAL_BLOCKS; i += 64)
                __hip_atomic_store(&flags[i], 0u, __ATOMIC_RELAXED,
                                   __HIP_MEMORY_SCOPE_AGENT);
        }
    }
}

extern "C" void kernel_launch(void* const* d_in, const int* in_sizes, int n_in,
                              void* d_out, int out_size, void* d_ws, size_t ws_size,
                              hipStream_t stream)
{
    const float* pcl    = (const float*)d_in[0];
    const float* trans  = (const float*)d_in[1];
    const float* rot    = (const float*)d_in[2];
    const float* sizep  = (const float*)d_in[3];
    const float* seps   = (const float*)d_in[4];
    const float* deform = (const float*)d_in[5];
    const float* probs  = (const float*)d_in[6];
    const float* etas   = (const float*)d_in[7];
    const float* omegas = (const float*)d_in[8];
    float* out = (float*)d_out;
    float* partials = (float*)d_ws;                       // [0, 5120) bytes
    unsigned int* flags = (unsigned int*)((char*)d_ws + 8192);  // [8192, 10240)

    k_all<<<TOTAL_BLOCKS, 256, 0, stream>>>(pcl, trans, rot, sizep, seps,
                                            deform, probs, etas, omegas,
                                            partials, flags, out);
}